// Round 14
// baseline (49.872 us; speedup 1.0000x reference)
//
#include <hip/hip_runtime.h>

// Separable QP projection. One 256-thread block per row (B=4096, N=4096).
//
// R13 post-mortem: load-free probes (uniform fast path) gave ZERO speedup,
// VALUBusy fell -> the probe phase is bound by serial ROUND latency
// (eval -> DPP reduce -> LDS -> barrier -> broadcast), not eval cost.
// R14: pack more shrink per round. FAST PATH: 4 probes/round -> 5x shrink
// per round -> 5 rounds = 3125x total (>= old 9-round scheme), then exact
// endpoint interpolation. Probes are pure VALU (za in regs + scalar
// g0/m0/M0); 4 independent DPP chains interleave; ONE barrier per round.
// GENERAL PATH (non-uniform gamma/m/M): verbatim R6 (proven, 34us).

#define ROUNDS 5           // fast path: 4 probes/round, 5x shrink/round
#define BISECT_STEPS 6     // general path (R6)
#define TOTAL_STEPS  9

// ---- DPP wave64 reduction helpers ----
template<int CTRL, int RM>
__device__ __forceinline__ float dpp_addf(float v) {
    int t = __builtin_amdgcn_update_dpp(0, __float_as_int(v), CTRL, RM, 0xf, false);
    return v + __int_as_float(t);
}
template<int CTRL, int RM>
__device__ __forceinline__ float dpp_minf(float v) {
    int t = __builtin_amdgcn_update_dpp(0x7f800000, __float_as_int(v), CTRL, RM, 0xf, false);
    return fminf(v, __int_as_float(t));
}
template<int CTRL, int RM>
__device__ __forceinline__ float dpp_maxf(float v) {
    int t = __builtin_amdgcn_update_dpp(0xff800000, __float_as_int(v), CTRL, RM, 0xf, false);
    return fmaxf(v, __int_as_float(t));
}
__device__ __forceinline__ float wave_sum(float v) {
    v = dpp_addf<0x111, 0xf>(v);
    v = dpp_addf<0x112, 0xf>(v);
    v = dpp_addf<0x114, 0xf>(v);
    v = dpp_addf<0x118, 0xf>(v);
    v = dpp_addf<0x142, 0xa>(v);
    v = dpp_addf<0x143, 0xc>(v);
    return __int_as_float(__builtin_amdgcn_readlane(__float_as_int(v), 63));
}
__device__ __forceinline__ float wave_min(float v) {
    v = dpp_minf<0x111, 0xf>(v);
    v = dpp_minf<0x112, 0xf>(v);
    v = dpp_minf<0x114, 0xf>(v);
    v = dpp_minf<0x118, 0xf>(v);
    v = dpp_minf<0x142, 0xa>(v);
    v = dpp_minf<0x143, 0xc>(v);
    return __int_as_float(__builtin_amdgcn_readlane(__float_as_int(v), 63));
}
__device__ __forceinline__ float wave_max(float v) {
    v = dpp_maxf<0x111, 0xf>(v);
    v = dpp_maxf<0x112, 0xf>(v);
    v = dpp_maxf<0x114, 0xf>(v);
    v = dpp_maxf<0x118, 0xf>(v);
    v = dpp_maxf<0x142, 0xa>(v);
    v = dpp_maxf<0x143, 0xc>(v);
    return __int_as_float(__builtin_amdgcn_readlane(__float_as_int(v), 63));
}

__global__ __launch_bounds__(256) void qp_proj_n4096(
    const float* __restrict__ z,
    const float* __restrict__ gamma,
    const float* __restrict__ mlo,
    const float* __restrict__ mhi,
    const float* __restrict__ xi,
    float* __restrict__ out)
{
    constexpr int N = 4096;
    const int row  = blockIdx.x;
    const int tid  = threadIdx.x;     // 0..255
    const int lane = tid & 63;
    const int wid  = tid >> 6;        // 0..3

    const float4* zrow = reinterpret_cast<const float4*>(z + (size_t)row * N);
    const float4* g4   = reinterpret_cast<const float4*>(gamma);
    const float4* m4   = reinterpret_cast<const float4*>(mlo);
    const float4* M4   = reinterpret_cast<const float4*>(mhi);
    float4*       orow = reinterpret_cast<float4*>(out + (size_t)row * N);

    __shared__ float red[8][4];
    __shared__ float wsum[2][4][4];   // [buf][probe][wave]; one barrier/round

    // ---- prologue: z into registers; min/max stats of z, g, m, M ----
    float za[16];
    float zmn =  INFINITY, zmx = -INFINITY;
    float gmn =  INFINITY, gmx = -INFINITY;
    float mmn =  INFINITY, mmx = -INFINITY;
    float Mmn =  INFINITY, Mmx = -INFINITY;

    #pragma unroll
    for (int k = 0; k < 4; ++k) {
        const int idx = tid + k * 256;           // float4 index, coalesced
        const float4 zz = zrow[idx];
        const float4 gg = g4[idx];
        const float4 mm = m4[idx];
        const float4 MM = M4[idx];
        za[4*k+0] = zz.x; za[4*k+1] = zz.y; za[4*k+2] = zz.z; za[4*k+3] = zz.w;
        zmn = fminf(zmn, fminf(fminf(zz.x, zz.y), fminf(zz.z, zz.w)));
        zmx = fmaxf(zmx, fmaxf(fmaxf(zz.x, zz.y), fmaxf(zz.z, zz.w)));
        gmn = fminf(gmn, fminf(fminf(gg.x, gg.y), fminf(gg.z, gg.w)));
        gmx = fmaxf(gmx, fmaxf(fmaxf(gg.x, gg.y), fmaxf(gg.z, gg.w)));
        mmn = fminf(mmn, fminf(fminf(mm.x, mm.y), fminf(mm.z, mm.w)));
        mmx = fmaxf(mmx, fmaxf(fmaxf(mm.x, mm.y), fmaxf(mm.z, mm.w)));
        Mmn = fminf(Mmn, fminf(fminf(MM.x, MM.y), fminf(MM.z, MM.w)));
        Mmx = fmaxf(Mmx, fmaxf(fmaxf(MM.x, MM.y), fmaxf(MM.z, MM.w)));
    }
    zmn = wave_min(zmn); zmx = wave_max(zmx);
    gmn = wave_min(gmn); gmx = wave_max(gmx);
    mmn = wave_min(mmn); mmx = wave_max(mmx);
    Mmn = wave_min(Mmn); Mmx = wave_max(Mmx);
    if (lane == 0) {
        red[0][wid] = zmn; red[1][wid] = zmx;
        red[2][wid] = gmn; red[3][wid] = gmx;
        red[4][wid] = mmn; red[5][wid] = mmx;
        red[6][wid] = Mmn; red[7][wid] = Mmx;
    }
    __syncthreads();
    const float zminT = fminf(fminf(red[0][0], red[0][1]), fminf(red[0][2], red[0][3]));
    const float zmaxT = fmaxf(fmaxf(red[1][0], red[1][1]), fmaxf(red[1][2], red[1][3]));
    const float gminT = fminf(fminf(red[2][0], red[2][1]), fminf(red[2][2], red[2][3]));
    const float gmaxT = fmaxf(fmaxf(red[3][0], red[3][1]), fmaxf(red[3][2], red[3][3]));
    const float mminT = fminf(fminf(red[4][0], red[4][1]), fminf(red[4][2], red[4][3]));
    const float mmaxT = fmaxf(fmaxf(red[5][0], red[5][1]), fmaxf(red[5][2], red[5][3]));
    const float MminT = fminf(fminf(red[6][0], red[6][1]), fminf(red[6][2], red[6][3]));
    const float MmaxT = fmaxf(fmaxf(red[7][0], red[7][1]), fmaxf(red[7][2], red[7][3]));

    const bool uniform = (gminT == gmaxT) && (mminT == mmaxT) &&
                         (MminT == MmaxT) && (gminT > 0.0f);
    const float xir = xi[row];

    if (uniform) {
        // ======= FAST PATH: 5 rounds x 4 probes (5x shrink/round) =======
        const float m0 = mminT, M0 = MminT;
        const float tg = 2.0f * gminT;
        const float ia = 1.0f / tg;
        float lo = tg * (m0 - zmaxT);      // all x clamp to m0 here
        float hi = tg * (M0 - zminT);      // all x clamp to M0 here
        float glo = (float)N * m0 - xir;   // <= 0
        float ghi = (float)N * M0 - xir;   // >= 0

        if (hi > lo) {
            for (int r = 0; r < ROUNDS; ++r) {
                const float w5 = 0.2f * (hi - lo);
                const float c1 = lo + w5;
                const float c2 = fmaf(2.0f, w5, lo);
                const float c3 = fmaf(3.0f, w5, lo);
                const float c4 = fmaf(4.0f, w5, lo);

                float s1 = 0.f, s2 = 0.f, s3 = 0.f, s4 = 0.f;
                #pragma unroll
                for (int j = 0; j < 16; ++j) {
                    const float zj = za[j];
                    s1 += __builtin_amdgcn_fmed3f(fmaf(c1, ia, zj), m0, M0);
                    s2 += __builtin_amdgcn_fmed3f(fmaf(c2, ia, zj), m0, M0);
                    s3 += __builtin_amdgcn_fmed3f(fmaf(c3, ia, zj), m0, M0);
                    s4 += __builtin_amdgcn_fmed3f(fmaf(c4, ia, zj), m0, M0);
                }
                // 4 independent DPP chains interleave
                s1 = wave_sum(s1);
                s2 = wave_sum(s2);
                s3 = wave_sum(s3);
                s4 = wave_sum(s4);

                const int p = r & 1;
                if (lane == 0) {
                    wsum[p][0][wid] = s1; wsum[p][1][wid] = s2;
                    wsum[p][2][wid] = s3; wsum[p][3][wid] = s4;
                }
                __syncthreads();
                // buf p's write at round r is protected from round r-2's
                // reads by the barrier at round r-1.
                const float g1 = ((wsum[p][0][0] + wsum[p][0][1]) + (wsum[p][0][2] + wsum[p][0][3])) - xir;
                const float g2 = ((wsum[p][1][0] + wsum[p][1][1]) + (wsum[p][1][2] + wsum[p][1][3])) - xir;
                const float g3 = ((wsum[p][2][0] + wsum[p][2][1]) + (wsum[p][2][2] + wsum[p][2][3])) - xir;
                const float g4v = ((wsum[p][3][0] + wsum[p][3][1]) + (wsum[p][3][2] + wsum[p][3][3])) - xir;

                // monotone g: root in sub-interval [cnt, cnt+1] of 5
                const int cnt = (g1 <= 0.0f) + (g2 <= 0.0f) + (g3 <= 0.0f) + (g4v <= 0.0f);
                const float nglo = (cnt == 0) ? glo : (cnt == 1 ? g1 : cnt == 2 ? g2 : cnt == 3 ? g3 : g4v);
                const float nghi = (cnt == 4) ? ghi : (cnt == 0 ? g1 : cnt == 1 ? g2 : cnt == 2 ? g3 : g4v);
                const float nlo  = fmaf((float)cnt, w5, lo);
                const float nhi  = (cnt == 4) ? hi : fmaf((float)(cnt + 1), w5, lo);
                lo = nlo; hi = nhi; glo = nglo; ghi = nghi;
            }
        }

        // exact endpoint interpolation (bracket ~6e-3 wide; <=1 breakpoint)
        const float denom = ghi - glo;
        float lam = (denom > 1e-30f) ? (lo * ghi - hi * glo) / denom
                                     : fmaf(0.5f, hi - lo, lo);
        lam = fminf(fmaxf(lam, lo), hi);

        // epilogue entirely from registers
        #pragma unroll
        for (int k = 0; k < 4; ++k) {
            const int idx = tid + k * 256;
            float4 r;
            r.x = __builtin_amdgcn_fmed3f(fmaf(lam, ia, za[4*k+0]), m0, M0);
            r.y = __builtin_amdgcn_fmed3f(fmaf(lam, ia, za[4*k+1]), m0, M0);
            r.z = __builtin_amdgcn_fmed3f(fmaf(lam, ia, za[4*k+2]), m0, M0);
            r.w = __builtin_amdgcn_fmed3f(fmaf(lam, ia, za[4*k+3]), m0, M0);
            orow[idx] = r;
        }
    } else {
        // =========== GENERAL PATH: verbatim R6 structure ===========
        __syncthreads();   // protect red[] reuse (anti-dependency)

        float ib[16], ma[16], Ma[16];
        float pmin =  INFINITY, pmax = -INFINITY, psm = 0.0f, psM = 0.0f;
        #pragma unroll
        for (int k = 0; k < 4; ++k) {
            const int idx = tid + k * 256;
            const float4 gg = g4[idx];
            const float4 mm = m4[idx];
            const float4 MM = M4[idx];
            const float gs[4] = {gg.x, gg.y, gg.z, gg.w};
            const float ms[4] = {mm.x, mm.y, mm.z, mm.w};
            const float Ms[4] = {MM.x, MM.y, MM.z, MM.w};
            #pragma unroll
            for (int c = 0; c < 4; ++c) {
                const int j = 4 * k + c;
                const float tg = 2.0f * gs[c];
                ib[j] = 1.0f / tg;
                ma[j] = ms[c];
                Ma[j] = Ms[c];
                pmin = fminf(pmin, tg * (ms[c] - za[j]));
                pmax = fmaxf(pmax, tg * (Ms[c] - za[j]));
                psm += ms[c];
                psM += Ms[c];
            }
        }
        pmin = wave_min(pmin);
        pmax = wave_max(pmax);
        psm  = wave_sum(psm);
        psM  = wave_sum(psM);
        if (lane == 0) { red[0][wid] = pmin; red[1][wid] = pmax;
                         red[2][wid] = psm;  red[3][wid] = psM; }
        __syncthreads();
        float lo = fminf(fminf(red[0][0], red[0][1]), fminf(red[0][2], red[0][3]));
        float hi = fmaxf(fmaxf(red[1][0], red[1][1]), fmaxf(red[1][2], red[1][3]));
        float glo = ((red[2][0] + red[2][1]) + (red[2][2] + red[2][3])) - xir;
        float ghi = ((red[3][0] + red[3][1]) + (red[3][2] + red[3][3])) - xir;
        int side = 0;

        for (int it = 0; it < TOTAL_STEPS; ++it) {
            const float w = hi - lo;
            float cand;
            if (it < BISECT_STEPS) {
                cand = fmaf(0.5f, w, lo);
            } else {
                const float denom = ghi - glo;
                cand = (lo * ghi - hi * glo) / denom;
                cand = fminf(fmaxf(cand, fmaf(0.0625f, w, lo)),
                             fmaf(-0.0625f, w, hi));
            }

            float t0 = 0.f, t1 = 0.f, t2 = 0.f, t3 = 0.f;
            #pragma unroll
            for (int q = 0; q < 4; ++q) {
                t0 += __builtin_amdgcn_fmed3f(fmaf(cand, ib[4*q+0], za[4*q+0]), ma[4*q+0], Ma[4*q+0]);
                t1 += __builtin_amdgcn_fmed3f(fmaf(cand, ib[4*q+1], za[4*q+1]), ma[4*q+1], Ma[4*q+1]);
                t2 += __builtin_amdgcn_fmed3f(fmaf(cand, ib[4*q+2], za[4*q+2]), ma[4*q+2], Ma[4*q+2]);
                t3 += __builtin_amdgcn_fmed3f(fmaf(cand, ib[4*q+3], za[4*q+3]), ma[4*q+3], Ma[4*q+3]);
            }
            const float sw = wave_sum((t0 + t1) + (t2 + t3));

            const int p = it & 1;
            if (lane == 0) wsum[p][0][wid] = sw;
            __syncthreads();
            const float s = ((wsum[p][0][0] + wsum[p][0][1]) + (wsum[p][0][2] + wsum[p][0][3])) - xir;

            if (s > 0.0f) {
                hi = cand;
                if (side == 1) glo *= 0.5f;
                ghi = s;
                side = 1;
            } else {
                lo = cand;
                if (side == -1) ghi *= 0.5f;
                glo = s;
                side = -1;
            }
        }

        const float denom = ghi - glo;
        float lam = (denom > 0.0f) ? (lo * ghi - hi * glo) / denom
                                   : fmaf(0.5f, hi - lo, lo);
        lam = fminf(fmaxf(lam, lo), hi);

        #pragma unroll
        for (int k = 0; k < 4; ++k) {
            const int idx = tid + k * 256;
            float4 r;
            float xs[4];
            #pragma unroll
            for (int c = 0; c < 4; ++c) {
                const int j = 4 * k + c;
                xs[c] = __builtin_amdgcn_fmed3f(fmaf(lam, ib[j], za[j]), ma[j], Ma[j]);
            }
            r.x = xs[0]; r.y = xs[1]; r.z = xs[2]; r.w = xs[3];
            orow[idx] = r;
        }
    }
}

extern "C" void kernel_launch(void* const* d_in, const int* in_sizes, int n_in,
                              void* d_out, int out_size, void* d_ws, size_t ws_size,
                              hipStream_t stream) {
    const float* z     = (const float*)d_in[0];
    const float* gamma = (const float*)d_in[1];
    const float* m     = (const float*)d_in[2];
    const float* M     = (const float*)d_in[3];
    const float* xi    = (const float*)d_in[4];
    float* out = (float*)d_out;

    const int B = in_sizes[4];   // rows (xi has one entry per row)
    // Kernel is specialized to N == 4096 (16 elements / thread, 256 threads).
    qp_proj_n4096<<<dim3(B), dim3(256), 0, stream>>>(z, gamma, m, M, xi, out);
}

// Round 15
// 35.814 us; speedup vs baseline: 1.3925x; 1.3925x over previous
//
#include <hip/hip_runtime.h>

// Separable QP projection. 4 ROWS PER BLOCK (1024 blocks of 256 threads),
// 16 elems/thread/row.
//
// R13/R14 post-mortem: dur ~= VALU-busy (~18us @ R13 op count) + memory
// floor (~15.4us), ADDITIVE (no overlap at ~3.4 blocks/CU). R15 attacks
// both terms: (1) uniformity check once per block via equality+ballot
// (~25 instr vs ~170/row of min/max chains); (2) 4 rows/block with next-row
// z prefetch issued before the current row's rounds (loads/stores overlap
// the round phase); (3) rounds 9->8 (6 bisect + 2 Illinois + exact interp).
// FAST PATH probes: za[16] in regs + scalar g0/m0/M0 (pure VALU, no loads).
// GENERAL PATH (non-uniform gamma/m/M): R6 logic per row (proven).

#define ROWS_PB 4
#define BISECT_STEPS 6
#define TOTAL_STEPS  8   // 6 bisection + 2 Illinois, then interpolate

// ---- DPP wave64 reduction helpers ----
template<int CTRL, int RM>
__device__ __forceinline__ float dpp_addf(float v) {
    int t = __builtin_amdgcn_update_dpp(0, __float_as_int(v), CTRL, RM, 0xf, false);
    return v + __int_as_float(t);
}
template<int CTRL, int RM>
__device__ __forceinline__ float dpp_minf(float v) {
    int t = __builtin_amdgcn_update_dpp(0x7f800000, __float_as_int(v), CTRL, RM, 0xf, false);
    return fminf(v, __int_as_float(t));
}
template<int CTRL, int RM>
__device__ __forceinline__ float dpp_maxf(float v) {
    int t = __builtin_amdgcn_update_dpp(0xff800000, __float_as_int(v), CTRL, RM, 0xf, false);
    return fmaxf(v, __int_as_float(t));
}
__device__ __forceinline__ float wave_sum(float v) {
    v = dpp_addf<0x111, 0xf>(v);
    v = dpp_addf<0x112, 0xf>(v);
    v = dpp_addf<0x114, 0xf>(v);
    v = dpp_addf<0x118, 0xf>(v);
    v = dpp_addf<0x142, 0xa>(v);
    v = dpp_addf<0x143, 0xc>(v);
    return __int_as_float(__builtin_amdgcn_readlane(__float_as_int(v), 63));
}
__device__ __forceinline__ float wave_min(float v) {
    v = dpp_minf<0x111, 0xf>(v);
    v = dpp_minf<0x112, 0xf>(v);
    v = dpp_minf<0x114, 0xf>(v);
    v = dpp_minf<0x118, 0xf>(v);
    v = dpp_minf<0x142, 0xa>(v);
    v = dpp_minf<0x143, 0xc>(v);
    return __int_as_float(__builtin_amdgcn_readlane(__float_as_int(v), 63));
}
__device__ __forceinline__ float wave_max(float v) {
    v = dpp_maxf<0x111, 0xf>(v);
    v = dpp_maxf<0x112, 0xf>(v);
    v = dpp_maxf<0x114, 0xf>(v);
    v = dpp_maxf<0x118, 0xf>(v);
    v = dpp_maxf<0x142, 0xa>(v);
    v = dpp_maxf<0x143, 0xc>(v);
    return __int_as_float(__builtin_amdgcn_readlane(__float_as_int(v), 63));
}

__global__ __launch_bounds__(256) void qp_proj_n4096(
    const float* __restrict__ z,
    const float* __restrict__ gamma,
    const float* __restrict__ mlo,
    const float* __restrict__ mhi,
    const float* __restrict__ xi,
    float* __restrict__ out,
    int Btot)
{
    constexpr int N = 4096;
    const int tid  = threadIdx.x;     // 0..255
    const int lane = tid & 63;
    const int wid  = tid >> 6;        // 0..3
    const int row0 = blockIdx.x * ROWS_PB;

    const float4* g4 = reinterpret_cast<const float4*>(gamma);
    const float4* m4 = reinterpret_cast<const float4*>(mlo);
    const float4* M4 = reinterpret_cast<const float4*>(mhi);

    __shared__ float red[2][2][4];    // [row parity][min|max][wave]
    __shared__ float wsum[2][4];      // round sums, double-buffered
    __shared__ float gred[4][4];      // general-path bounds reduce
    __shared__ int   uni[4];

    // ---- uniformity check: ONCE per block, equality vs element 0 ----
    const float g0 = gamma[0];
    const float m0 = mlo[0];
    const float M0 = mhi[0];
    bool ok = (g0 > 0.0f) && (M0 > m0);
    #pragma unroll
    for (int k = 0; k < 4; ++k) {
        const int idx = tid + k * 256;
        const float4 gg = g4[idx];
        const float4 mm = m4[idx];
        const float4 MM = M4[idx];
        ok = ok && (gg.x == g0) && (gg.y == g0) && (gg.z == g0) && (gg.w == g0)
                && (mm.x == m0) && (mm.y == m0) && (mm.z == m0) && (mm.w == m0)
                && (MM.x == M0) && (MM.y == M0) && (MM.z == M0) && (MM.w == M0);
    }
    {
        const unsigned long long bal = __ballot(ok);
        if (lane == 0) uni[wid] = (bal == 0xFFFFFFFFFFFFFFFFull) ? 1 : 0;
    }
    __syncthreads();
    const bool uniform = uni[0] && uni[1] && uni[2] && uni[3];

    if (uniform) {
        // ================= FAST PATH: 4-row pipeline =================
        const float tg = 2.0f * g0;
        const float ia = 1.0f / tg;
        const float gloC = (float)N * m0;   // sum at lam=lo (all at m0)
        const float ghiC = (float)N * M0;   // sum at lam=hi (all at M0)

        // preload row 0
        float za[16];
        {
            const float4* zr = reinterpret_cast<const float4*>(z + (size_t)row0 * N);
            #pragma unroll
            for (int k = 0; k < 4; ++k) {
                const float4 zz = zr[tid + k * 256];
                za[4*k+0] = zz.x; za[4*k+1] = zz.y; za[4*k+2] = zz.z; za[4*k+3] = zz.w;
            }
        }

        #pragma unroll
        for (int r = 0; r < ROWS_PB; ++r) {
            const int row = row0 + r;
            if (row >= Btot) break;                 // block-uniform

            // prefetch next row's z (issue now; consumed after rounds)
            float zb[16];
            const bool hasNext = (r + 1 < ROWS_PB) && (row + 1 < Btot);
            if (hasNext) {
                const float4* zr = reinterpret_cast<const float4*>(z + (size_t)(row + 1) * N);
                #pragma unroll
                for (int k = 0; k < 4; ++k) {
                    const float4 zz = zr[tid + k * 256];
                    zb[4*k+0] = zz.x; zb[4*k+1] = zz.y; zb[4*k+2] = zz.z; zb[4*k+3] = zz.w;
                }
            }

            // ---- z stats -> bracket ----
            float zmn = INFINITY, zmx = -INFINITY;
            #pragma unroll
            for (int j = 0; j < 16; ++j) {
                zmn = fminf(zmn, za[j]);
                zmx = fmaxf(zmx, za[j]);
            }
            zmn = wave_min(zmn);
            zmx = wave_max(zmx);
            const int pr = r & 1;
            if (lane == 0) { red[pr][0][wid] = zmn; red[pr][1][wid] = zmx; }
            __syncthreads();
            const float zminT = fminf(fminf(red[pr][0][0], red[pr][0][1]),
                                      fminf(red[pr][0][2], red[pr][0][3]));
            const float zmaxT = fmaxf(fmaxf(red[pr][1][0], red[pr][1][1]),
                                      fmaxf(red[pr][1][2], red[pr][1][3]));
            const float xir = xi[row];

            float lo  = tg * (m0 - zmaxT);
            float hi  = tg * (M0 - zminT);
            float glo = gloC - xir;                 // <= 0
            float ghi = ghiC - xir;                 // >= 0
            int side = 0;

            // ---- 6 bisection + 2 Illinois rounds ----
            for (int it = 0; it < TOTAL_STEPS; ++it) {
                const float w = hi - lo;
                float cand;
                if (it < BISECT_STEPS) {
                    cand = fmaf(0.5f, w, lo);
                } else {
                    const float denom = ghi - glo;          // > 0
                    cand = (lo * ghi - hi * glo) / denom;
                    cand = fminf(fmaxf(cand, fmaf(0.0625f, w, lo)),
                                 fmaf(-0.0625f, w, hi));    // strictly interior
                }

                float t0 = 0.f, t1 = 0.f, t2 = 0.f, t3 = 0.f;
                #pragma unroll
                for (int q = 0; q < 4; ++q) {
                    t0 += __builtin_amdgcn_fmed3f(fmaf(cand, ia, za[4*q+0]), m0, M0);
                    t1 += __builtin_amdgcn_fmed3f(fmaf(cand, ia, za[4*q+1]), m0, M0);
                    t2 += __builtin_amdgcn_fmed3f(fmaf(cand, ia, za[4*q+2]), m0, M0);
                    t3 += __builtin_amdgcn_fmed3f(fmaf(cand, ia, za[4*q+3]), m0, M0);
                }
                const float sw = wave_sum((t0 + t1) + (t2 + t3));

                const int p = it & 1;
                if (lane == 0) wsum[p][wid] = sw;
                __syncthreads();
                const float s = ((wsum[p][0] + wsum[p][1]) + (wsum[p][2] + wsum[p][3])) - xir;

                if (s > 0.0f) {
                    hi = cand;
                    if (side == 1) glo *= 0.5f;     // Illinois halving
                    ghi = s;
                    side = 1;
                } else {
                    lo = cand;
                    if (side == -1) ghi *= 0.5f;
                    glo = s;
                    side = -1;
                }
            }

            const float denom = ghi - glo;
            float lam = (denom > 0.0f) ? (lo * ghi - hi * glo) / denom
                                       : fmaf(0.5f, hi - lo, lo);
            lam = fminf(fmaxf(lam, lo), hi);

            // ---- epilogue from registers ----
            {
                float4* orow = reinterpret_cast<float4*>(out + (size_t)row * N);
                #pragma unroll
                for (int k = 0; k < 4; ++k) {
                    float4 rr;
                    rr.x = __builtin_amdgcn_fmed3f(fmaf(lam, ia, za[4*k+0]), m0, M0);
                    rr.y = __builtin_amdgcn_fmed3f(fmaf(lam, ia, za[4*k+1]), m0, M0);
                    rr.z = __builtin_amdgcn_fmed3f(fmaf(lam, ia, za[4*k+2]), m0, M0);
                    rr.w = __builtin_amdgcn_fmed3f(fmaf(lam, ia, za[4*k+3]), m0, M0);
                    orow[tid + k * 256] = rr;
                }
            }

            // rotate prefetched row into za
            if (hasNext) {
                #pragma unroll
                for (int j = 0; j < 16; ++j) za[j] = zb[j];
            }
        }
    } else {
        // ============ GENERAL PATH: R6 logic per row ============
        for (int r = 0; r < ROWS_PB; ++r) {
            const int row = row0 + r;
            if (row >= Btot) break;                 // block-uniform

            const float4* zr = reinterpret_cast<const float4*>(z + (size_t)row * N);
            float4* orow = reinterpret_cast<float4*>(out + (size_t)row * N);

            float za[16], ib[16], ma[16], Ma[16];
            float pmin = INFINITY, pmax = -INFINITY, psm = 0.0f, psM = 0.0f;
            #pragma unroll
            for (int k = 0; k < 4; ++k) {
                const int idx = tid + k * 256;
                const float4 zz = zr[idx];
                const float4 gg = g4[idx];
                const float4 mm = m4[idx];
                const float4 MM = M4[idx];
                const float zs[4] = {zz.x, zz.y, zz.z, zz.w};
                const float gs[4] = {gg.x, gg.y, gg.z, gg.w};
                const float ms[4] = {mm.x, mm.y, mm.z, mm.w};
                const float Ms[4] = {MM.x, MM.y, MM.z, MM.w};
                #pragma unroll
                for (int c = 0; c < 4; ++c) {
                    const int j = 4 * k + c;
                    const float tg2 = 2.0f * gs[c];
                    za[j] = zs[c];
                    ib[j] = 1.0f / tg2;
                    ma[j] = ms[c];
                    Ma[j] = Ms[c];
                    pmin = fminf(pmin, tg2 * (ms[c] - zs[c]));
                    pmax = fmaxf(pmax, tg2 * (Ms[c] - zs[c]));
                    psm += ms[c];
                    psM += Ms[c];
                }
            }
            pmin = wave_min(pmin);
            pmax = wave_max(pmax);
            psm  = wave_sum(psm);
            psM  = wave_sum(psM);
            if (lane == 0) { gred[0][wid] = pmin; gred[1][wid] = pmax;
                             gred[2][wid] = psm;  gred[3][wid] = psM; }
            __syncthreads();
            float lo = fminf(fminf(gred[0][0], gred[0][1]), fminf(gred[0][2], gred[0][3]));
            float hi = fmaxf(fmaxf(gred[1][0], gred[1][1]), fmaxf(gred[1][2], gred[1][3]));
            const float xir = xi[row];
            float glo = ((gred[2][0] + gred[2][1]) + (gred[2][2] + gred[2][3])) - xir;
            float ghi = ((gred[3][0] + gred[3][1]) + (gred[3][2] + gred[3][3])) - xir;
            int side = 0;

            for (int it = 0; it < TOTAL_STEPS + 1; ++it) {   // 9 steps (proven R6)
                const float w = hi - lo;
                float cand;
                if (it < BISECT_STEPS) {
                    cand = fmaf(0.5f, w, lo);
                } else {
                    const float denom = ghi - glo;
                    cand = (lo * ghi - hi * glo) / denom;
                    cand = fminf(fmaxf(cand, fmaf(0.0625f, w, lo)),
                                 fmaf(-0.0625f, w, hi));
                }

                float t0 = 0.f, t1 = 0.f, t2 = 0.f, t3 = 0.f;
                #pragma unroll
                for (int q = 0; q < 4; ++q) {
                    t0 += __builtin_amdgcn_fmed3f(fmaf(cand, ib[4*q+0], za[4*q+0]), ma[4*q+0], Ma[4*q+0]);
                    t1 += __builtin_amdgcn_fmed3f(fmaf(cand, ib[4*q+1], za[4*q+1]), ma[4*q+1], Ma[4*q+1]);
                    t2 += __builtin_amdgcn_fmed3f(fmaf(cand, ib[4*q+2], za[4*q+2]), ma[4*q+2], Ma[4*q+2]);
                    t3 += __builtin_amdgcn_fmed3f(fmaf(cand, ib[4*q+3], za[4*q+3]), ma[4*q+3], Ma[4*q+3]);
                }
                const float sw = wave_sum((t0 + t1) + (t2 + t3));

                const int p = it & 1;
                if (lane == 0) wsum[p][wid] = sw;
                __syncthreads();
                const float s = ((wsum[p][0] + wsum[p][1]) + (wsum[p][2] + wsum[p][3])) - xir;

                if (s > 0.0f) {
                    hi = cand;
                    if (side == 1) glo *= 0.5f;
                    ghi = s;
                    side = 1;
                } else {
                    lo = cand;
                    if (side == -1) ghi *= 0.5f;
                    glo = s;
                    side = -1;
                }
            }

            const float denom = ghi - glo;
            float lam = (denom > 0.0f) ? (lo * ghi - hi * glo) / denom
                                       : fmaf(0.5f, hi - lo, lo);
            lam = fminf(fmaxf(lam, lo), hi);

            #pragma unroll
            for (int k = 0; k < 4; ++k) {
                float4 rr;
                float xs[4];
                #pragma unroll
                for (int c = 0; c < 4; ++c) {
                    const int j = 4 * k + c;
                    xs[c] = __builtin_amdgcn_fmed3f(fmaf(lam, ib[j], za[j]), ma[j], Ma[j]);
                }
                rr.x = xs[0]; rr.y = xs[1]; rr.z = xs[2]; rr.w = xs[3];
                orow[tid + k * 256] = rr;
            }
            __syncthreads();   // protect gred/wsum reuse across rows
        }
    }
}

extern "C" void kernel_launch(void* const* d_in, const int* in_sizes, int n_in,
                              void* d_out, int out_size, void* d_ws, size_t ws_size,
                              hipStream_t stream) {
    const float* z     = (const float*)d_in[0];
    const float* gamma = (const float*)d_in[1];
    const float* m     = (const float*)d_in[2];
    const float* M     = (const float*)d_in[3];
    const float* xi    = (const float*)d_in[4];
    float* out = (float*)d_out;

    const int B = in_sizes[4];   // rows (xi has one entry per row)
    const int nblocks = (B + ROWS_PB - 1) / ROWS_PB;
    // Kernel specialized to N == 4096 (16 elements/thread/row, 256 threads).
    qp_proj_n4096<<<dim3(nblocks), dim3(256), 0, stream>>>(z, gamma, m, M, xi, out, B);
}